// Round 2
// baseline (881.301 us; speedup 1.0000x reference)
//
#include <hip/hip_runtime.h>

// GraphSAGE layer: B=8, N=5000, E=100000, D=128 (in==out dim)
// All float tensors are float32 (per reference); edge_index is int32.
// Inputs: node_features[B,N,D], edge_index[B,2,E], node_mask[B,N],
// edge_mask[B,E], W_self[D,D], b_self[D], W_nb[D,D], b_nb[D], gamma[D], beta[D].
// Output: float32 [B,N,D].

#define B_ 8
#define N_ 5000
#define E_ 100000
#define D_ 128
#define EPS_ 1e-5f
#define NPB 8   // nodes per block in the fused kernel

// One wave (64 lanes) per edge: lane i handles dims 2i, 2i+1.
// sums[b,tgt,:] += x[b,src,:] * em;  cnt[b,tgt] += em
__global__ __launch_bounds__(256) void scatter_k(
    const float* __restrict__ x, const int* __restrict__ ei,
    const float* __restrict__ em, float* __restrict__ sums,
    float* __restrict__ cnt)
{
    int wave_in_block = threadIdx.x >> 6;
    int lane = threadIdx.x & 63;
    int eidx = blockIdx.x * 4 + wave_in_block;          // global edge id, < 800000
    if (eidx >= B_ * E_) return;
    int b = eidx / E_;
    int e = eidx - b * E_;
    const int* eib = ei + (size_t)b * 2 * E_;
    int src = eib[e];
    int tgt = eib[E_ + e];
    float m = em[(size_t)b * E_ + e];
    if (m == 0.0f) return;
    const float* xp = x + ((size_t)b * N_ + src) * D_;
    float2 v = *(const float2*)(xp + 2 * lane);
    float* sp = sums + ((size_t)b * N_ + tgt) * D_ + 2 * lane;
    __hip_atomic_fetch_add(sp,     v.x * m, __ATOMIC_RELAXED, __HIP_MEMORY_SCOPE_AGENT);
    __hip_atomic_fetch_add(sp + 1, v.y * m, __ATOMIC_RELAXED, __HIP_MEMORY_SCOPE_AGENT);
    if (lane == 0)
        __hip_atomic_fetch_add(cnt + (size_t)b * N_ + tgt, m,
                               __ATOMIC_RELAXED, __HIP_MEMORY_SCOPE_AGENT);
}

// One block (128 threads = 2 waves) handles NPB nodes; thread = output channel o.
// self = x@Wself + bself ; nb = (sums/max(cnt,1))@Wnb + bnb ;
// h = relu(self+nb); LayerNorm over o; * gamma,beta; * node_mask.
__global__ __launch_bounds__(128) void fused_k(
    const float* __restrict__ x, const float* __restrict__ sums,
    const float* __restrict__ cnt, const float* __restrict__ Wself,
    const float* __restrict__ bself, const float* __restrict__ Wnb,
    const float* __restrict__ bnb, const float* __restrict__ gamma,
    const float* __restrict__ beta, const float* __restrict__ nmask,
    float* __restrict__ out)
{
    __shared__ float xs[NPB][D_];
    __shared__ float as[NPB][D_];
    __shared__ float red[2][2][NPB];   // [wave][sum/sumsq][node]

    int o = threadIdx.x;               // 0..127 output channel
    size_t base = (size_t)blockIdx.x * NPB;

    #pragma unroll
    for (int j = 0; j < NPB; ++j) {
        size_t node = base + j;
        xs[j][o] = x[node * D_ + o];
        float c = cnt[node];
        float inv = 1.0f / fmaxf(c, 1.0f);
        as[j][o] = sums[node * D_ + o] * inv;
    }
    __syncthreads();

    float accS[NPB], accN[NPB];
    float bs = bself[o], bn = bnb[o];
    #pragma unroll
    for (int j = 0; j < NPB; ++j) { accS[j] = bs; accN[j] = bn; }

    const float4* xs4 = (const float4*)xs;
    const float4* as4 = (const float4*)as;

    for (int d4 = 0; d4 < D_ / 4; ++d4) {
        int d = d4 * 4;
        float w0 = Wself[(size_t)(d + 0) * D_ + o];
        float w1 = Wself[(size_t)(d + 1) * D_ + o];
        float w2 = Wself[(size_t)(d + 2) * D_ + o];
        float w3 = Wself[(size_t)(d + 3) * D_ + o];
        float u0 = Wnb[(size_t)(d + 0) * D_ + o];
        float u1 = Wnb[(size_t)(d + 1) * D_ + o];
        float u2 = Wnb[(size_t)(d + 2) * D_ + o];
        float u3 = Wnb[(size_t)(d + 3) * D_ + o];
        #pragma unroll
        for (int j = 0; j < NPB; ++j) {
            float4 xv = xs4[j * (D_ / 4) + d4];   // LDS broadcast (all lanes same addr)
            float4 av = as4[j * (D_ / 4) + d4];
            accS[j] += xv.x * w0 + xv.y * w1 + xv.z * w2 + xv.w * w3;
            accN[j] += av.x * u0 + av.y * u1 + av.z * u2 + av.w * u3;
        }
    }

    // h = relu(self + nb), then LayerNorm across the 128 channels (2 waves).
    int lane = o & 63, wid = o >> 6;
    float hv[NPB], s[NPB], q[NPB];
    #pragma unroll
    for (int j = 0; j < NPB; ++j) {
        float h = fmaxf(accS[j] + accN[j], 0.0f);
        hv[j] = h; s[j] = h; q[j] = h * h;
    }
    #pragma unroll
    for (int off = 32; off >= 1; off >>= 1) {
        #pragma unroll
        for (int j = 0; j < NPB; ++j) {
            s[j] += __shfl_xor(s[j], off, 64);
            q[j] += __shfl_xor(q[j], off, 64);
        }
    }
    if (lane == 0) {
        #pragma unroll
        for (int j = 0; j < NPB; ++j) { red[wid][0][j] = s[j]; red[wid][1][j] = q[j]; }
    }
    __syncthreads();

    float g = gamma[o], bt = beta[o];
    #pragma unroll
    for (int j = 0; j < NPB; ++j) {
        float S = red[0][0][j] + red[1][0][j];
        float Q = red[0][1][j] + red[1][1][j];
        float mu  = S * (1.0f / D_);
        float var = Q * (1.0f / D_) - mu * mu;
        float rin = rsqrtf(fmaxf(var, 0.0f) + EPS_);
        size_t node = base + j;
        float mk = nmask[node];
        float v = (hv[j] - mu) * rin * g + bt;
        out[node * D_ + o] = v * mk;
    }
}

extern "C" void kernel_launch(void* const* d_in, const int* in_sizes, int n_in,
                              void* d_out, int out_size, void* d_ws, size_t ws_size,
                              hipStream_t stream)
{
    const float* x     = (const float*)d_in[0];
    const int*   ei    = (const int*)d_in[1];
    const float* nmask = (const float*)d_in[2];
    const float* em    = (const float*)d_in[3];
    const float* Wself = (const float*)d_in[4];
    const float* bself = (const float*)d_in[5];
    const float* Wnb   = (const float*)d_in[6];
    const float* bnb   = (const float*)d_in[7];
    const float* gamma = (const float*)d_in[8];
    const float* beta  = (const float*)d_in[9];
    float* out = (float*)d_out;

    float* sums = (float*)d_ws;                       // [B*N*D] f32
    float* cnt  = sums + (size_t)B_ * N_ * D_;        // [B*N]   f32
    size_t zero_bytes = ((size_t)B_ * N_ * D_ + (size_t)B_ * N_) * sizeof(float);
    hipMemsetAsync(d_ws, 0, zero_bytes, stream);

    int total_edges = B_ * E_;                        // 800000
    int blocksS = (total_edges + 3) / 4;              // 4 waves (edges) per 256-thr block
    scatter_k<<<blocksS, 256, 0, stream>>>(x, ei, em, sums, cnt);

    int blocksF = (B_ * N_) / NPB;                    // 40000/8 = 5000
    fused_k<<<blocksF, 128, 0, stream>>>(x, sums, cnt, Wself, bself, Wnb, bnb,
                                         gamma, beta, nmask, out);
}

// Round 3
// 568.908 us; speedup vs baseline: 1.5491x; 1.5491x over previous
//
#include <hip/hip_runtime.h>

// GraphSAGE layer: B=8, N=5000, E=100000, D=128. All float tensors f32; edge_index int32.
// Pipeline: memset(deg) -> hist_k -> scan_k (CSR offsets) -> fill_k (edge lists)
//           -> fused_k (gather+mean + dual GEMV + ReLU + LayerNorm + mask).
// R2 post-mortem: 103M f32 atomics ran at a request-rate ceiling (146 G/s, 8 B/atomic
// memory-side traffic, HBM only 17%). CSR+gather removes them.

#define B_ 8
#define N_ 5000
#define E_ 100000
#define D_ 128
#define EPS_ 1e-5f
#define NPB 32            // nodes per block in fused_k
#define NNODES (B_ * N_)  // 40000
#define NEDGES (B_ * E_)  // 800000

// ---------- CSR build ----------

__global__ __launch_bounds__(256) void hist_k(
    const int* __restrict__ ei, const float* __restrict__ em,
    int* __restrict__ deg)
{
    int idx = blockIdx.x * 256 + threadIdx.x;
    if (idx >= NEDGES) return;
    unsigned int b = (unsigned int)idx / E_;
    unsigned int e = (unsigned int)idx - b * E_;
    int tgt = ei[(size_t)b * 2 * E_ + E_ + e];
    float m = em[(size_t)b * E_ + e];
    if (m != 0.0f)
        atomicAdd(&deg[b * N_ + tgt], 1);
}

// Single-block exclusive scan over NNODES degrees -> offs; cursor = copy.
__global__ __launch_bounds__(1024) void scan_k(
    const int* __restrict__ deg, int* __restrict__ offs, int* __restrict__ cursor)
{
    __shared__ int partial[1024];
    const int CH = (NNODES + 1023) / 1024;   // 40
    int t = threadIdx.x;
    int base = t * CH;
    int s = 0;
    for (int k = 0; k < CH; ++k) {
        int i = base + k;
        if (i < NNODES) s += deg[i];
    }
    partial[t] = s;
    __syncthreads();
    for (int off = 1; off < 1024; off <<= 1) {
        int v = (t >= off) ? partial[t - off] : 0;
        __syncthreads();
        partial[t] += v;
        __syncthreads();
    }
    int running = (t == 0) ? 0 : partial[t - 1];   // exclusive base for my chunk
    for (int k = 0; k < CH; ++k) {
        int i = base + k;
        if (i < NNODES) {
            offs[i] = running;
            cursor[i] = running;
            running += deg[i];
        }
    }
}

// entries[slot] = { global_src_row, bitcast(m) }
__global__ __launch_bounds__(256) void fill_k(
    const int* __restrict__ ei, const float* __restrict__ em,
    int* __restrict__ cursor, int2* __restrict__ entries)
{
    int idx = blockIdx.x * 256 + threadIdx.x;
    if (idx >= NEDGES) return;
    unsigned int b = (unsigned int)idx / E_;
    unsigned int e = (unsigned int)idx - b * E_;
    const int* eib = ei + (size_t)b * 2 * E_;
    int src = eib[e];
    int tgt = eib[E_ + e];
    float m = em[(size_t)b * E_ + e];
    if (m != 0.0f) {
        int g = b * N_ + tgt;
        int slot = atomicAdd(&cursor[g], 1);
        entries[slot] = make_int2((int)(b * N_) + src, __float_as_int(m));
    }
}

// ---------- fused gather + GEMV + LN ----------
// 128 threads (2 waves), 32 nodes/block.
// Phase 1 (channel = tid): stage x rows and gathered means into LDS.
// Phase 2 (32-lane group = 8 nodes, thread = 4 contiguous channels):
//   dual GEMV from LDS broadcasts, ReLU, in-register LayerNorm, float4 store.
__global__ __launch_bounds__(128) void fused_k(
    const float* __restrict__ x, const int* __restrict__ deg,
    const int* __restrict__ offs, const int2* __restrict__ entries,
    const float* __restrict__ Wself, const float* __restrict__ bself,
    const float* __restrict__ Wnb, const float* __restrict__ bnb,
    const float* __restrict__ gamma, const float* __restrict__ beta,
    const float* __restrict__ nmask, float* __restrict__ out)
{
    __shared__ float xs[NPB][D_];
    __shared__ float as[NPB][D_];

    int t = threadIdx.x;                 // 0..127 = channel in phase 1
    int g0 = blockIdx.x * NPB;

    #pragma unroll 4
    for (int j = 0; j < NPB; ++j)
        xs[j][t] = x[(size_t)(g0 + j) * D_ + t];

    for (int j = 0; j < NPB; ++j) {
        int g = g0 + j;
        int dg = deg[g];
        int off = offs[g];
        float acc0 = 0.f, acc1 = 0.f, cnt0 = 0.f, cnt1 = 0.f;
        int k = 0;
        for (; k + 1 < dg; k += 2) {
            int2 e0 = entries[off + k];
            int2 e1 = entries[off + k + 1];
            float m0 = __int_as_float(e0.y);
            float m1 = __int_as_float(e1.y);
            acc0 += x[(size_t)e0.x * D_ + t] * m0;
            acc1 += x[(size_t)e1.x * D_ + t] * m1;
            cnt0 += m0;
            cnt1 += m1;
        }
        if (k < dg) {
            int2 e0 = entries[off + k];
            float m0 = __int_as_float(e0.y);
            acc0 += x[(size_t)e0.x * D_ + t] * m0;
            cnt0 += m0;
        }
        float cnt = cnt0 + cnt1;
        as[j][t] = (acc0 + acc1) * (1.0f / fmaxf(cnt, 1.0f));
    }
    __syncthreads();

    // Phase 2 lane roles
    int lane = t & 63;
    int wv = t >> 6;
    int grp = wv * 2 + (lane >> 5);      // 0..3 -> node group
    int c0 = lane & 31;                  // channel quad index: channels 4c0..4c0+3
    int jb = grp * 8;                    // first node of my group

    float4 bs4 = *(const float4*)(bself + 4 * c0);
    float4 bn4 = *(const float4*)(bnb + 4 * c0);
    float4 accS[8], accN[8];
    #pragma unroll
    for (int jj = 0; jj < 8; ++jj) { accS[jj] = bs4; accN[jj] = bn4; }

    for (int d = 0; d < D_; d += 4) {
        float4 w0 = *(const float4*)(Wself + (size_t)(d + 0) * D_ + 4 * c0);
        float4 w1 = *(const float4*)(Wself + (size_t)(d + 1) * D_ + 4 * c0);
        float4 w2 = *(const float4*)(Wself + (size_t)(d + 2) * D_ + 4 * c0);
        float4 w3 = *(const float4*)(Wself + (size_t)(d + 3) * D_ + 4 * c0);
        float4 u0 = *(const float4*)(Wnb  + (size_t)(d + 0) * D_ + 4 * c0);
        float4 u1 = *(const float4*)(Wnb  + (size_t)(d + 1) * D_ + 4 * c0);
        float4 u2 = *(const float4*)(Wnb  + (size_t)(d + 2) * D_ + 4 * c0);
        float4 u3 = *(const float4*)(Wnb  + (size_t)(d + 3) * D_ + 4 * c0);
        #pragma unroll
        for (int jj = 0; jj < 8; ++jj) {
            float4 xv = *(const float4*)(&xs[jb + jj][d]);   // 2-way broadcast / wave
            float4 av = *(const float4*)(&as[jb + jj][d]);
            accS[jj].x += xv.x * w0.x + xv.y * w1.x + xv.z * w2.x + xv.w * w3.x;
            accS[jj].y += xv.x * w0.y + xv.y * w1.y + xv.z * w2.y + xv.w * w3.y;
            accS[jj].z += xv.x * w0.z + xv.y * w1.z + xv.z * w2.z + xv.w * w3.z;
            accS[jj].w += xv.x * w0.w + xv.y * w1.w + xv.z * w2.w + xv.w * w3.w;
            accN[jj].x += av.x * u0.x + av.y * u1.x + av.z * u2.x + av.w * u3.x;
            accN[jj].y += av.x * u0.y + av.y * u1.y + av.z * u2.y + av.w * u3.y;
            accN[jj].z += av.x * u0.z + av.y * u1.z + av.z * u2.z + av.w * u3.z;
            accN[jj].w += av.x * u0.w + av.y * u1.w + av.z * u2.w + av.w * u3.w;
        }
    }

    float4 g4 = *(const float4*)(gamma + 4 * c0);
    float4 b4 = *(const float4*)(beta + 4 * c0);

    #pragma unroll
    for (int jj = 0; jj < 8; ++jj) {
        float4 h;
        h.x = fmaxf(accS[jj].x + accN[jj].x, 0.0f);
        h.y = fmaxf(accS[jj].y + accN[jj].y, 0.0f);
        h.z = fmaxf(accS[jj].z + accN[jj].z, 0.0f);
        h.w = fmaxf(accS[jj].w + accN[jj].w, 0.0f);
        float s = h.x + h.y + h.z + h.w;
        float q = h.x * h.x + h.y * h.y + h.z * h.z + h.w * h.w;
        #pragma unroll
        for (int off = 16; off >= 1; off >>= 1) {   // stays within 32-lane group
            s += __shfl_xor(s, off, 64);
            q += __shfl_xor(q, off, 64);
        }
        float mu = s * (1.0f / D_);
        float var = q * (1.0f / D_) - mu * mu;
        float rin = rsqrtf(fmaxf(var, 0.0f) + EPS_);
        int g = g0 + jb + jj;
        float mk = nmask[g];
        float4 v;
        v.x = ((h.x - mu) * rin * g4.x + b4.x) * mk;
        v.y = ((h.y - mu) * rin * g4.y + b4.y) * mk;
        v.z = ((h.z - mu) * rin * g4.z + b4.z) * mk;
        v.w = ((h.w - mu) * rin * g4.w + b4.w) * mk;
        *(float4*)(out + (size_t)g * D_ + 4 * c0) = v;
    }
}

extern "C" void kernel_launch(void* const* d_in, const int* in_sizes, int n_in,
                              void* d_out, int out_size, void* d_ws, size_t ws_size,
                              hipStream_t stream)
{
    const float* x     = (const float*)d_in[0];
    const int*   ei    = (const int*)d_in[1];
    const float* nmask = (const float*)d_in[2];
    const float* em    = (const float*)d_in[3];
    const float* Wself = (const float*)d_in[4];
    const float* bself = (const float*)d_in[5];
    const float* Wnb   = (const float*)d_in[6];
    const float* bnb   = (const float*)d_in[7];
    const float* gamma = (const float*)d_in[8];
    const float* beta  = (const float*)d_in[9];
    float* out = (float*)d_out;

    // ws layout: deg[40000] | offs[40000] | cursor[40000] | entries int2[800000]
    int* deg     = (int*)d_ws;
    int* offsets = deg + NNODES;
    int* cursor  = offsets + NNODES;
    int2* entries = (int2*)(cursor + NNODES);   // byte offset 480000, 8B-aligned

    hipMemsetAsync(deg, 0, NNODES * sizeof(int), stream);

    int blocksE = (NEDGES + 255) / 256;   // 3125
    hist_k<<<blocksE, 256, 0, stream>>>(ei, em, deg);
    scan_k<<<1, 1024, 0, stream>>>(deg, offsets, cursor);
    fill_k<<<blocksE, 256, 0, stream>>>(ei, em, cursor, entries);

    int blocksF = NNODES / NPB;           // 1250
    fused_k<<<blocksF, 128, 0, stream>>>(x, deg, offsets, entries,
                                         Wself, bself, Wnb, bnb,
                                         gamma, beta, nmask, out);
}

// Round 4
// 293.997 us; speedup vs baseline: 2.9977x; 1.9351x over previous
//
#include <hip/hip_runtime.h>

// GraphSAGE layer: B=8, N=5000, E=100000, D=128. All float tensors f32; edge_index int32.
// Pipeline: memset(deg) -> hist -> scanA/scanC (two-level CSR offsets in `cursor`)
//           -> fill (edge lists) -> gather (wave/node, XCD-swizzled, bf16 agg)
//           -> gemv_ln (dual GEMV + ReLU + LayerNorm + mask).
// R3 post-mortem: fused gather was latency-bound (Occ 14.6%, VALU 18.5%) and the
// single-block scan burned ~100+ us; x re-fetched 8x from HBM (159 MB) due to
// cross-XCD random gathers.

#define B_ 8
#define N_ 5000
#define E_ 100000
#define D_ 128
#define EPS_ 1e-5f
#define NPB 32            // nodes per block in gemv_ln_k
#define NNODES (B_ * N_)  // 40000
#define NEDGES (B_ * E_)  // 800000

static __device__ __forceinline__ unsigned short f2bf(float f) {
    union { float f; unsigned int i; } c; c.f = f;
    unsigned int i = c.i;
    i += 0x7fffu + ((i >> 16) & 1u);
    return (unsigned short)(i >> 16);
}
static __device__ __forceinline__ float bf2f(unsigned short u) {
    union { unsigned int i; float f; } c; c.i = ((unsigned int)u) << 16; return c.f;
}

// ---------- CSR build ----------

__global__ __launch_bounds__(256) void hist_k(
    const int* __restrict__ ei, const float* __restrict__ em,
    int* __restrict__ deg)
{
    int idx = blockIdx.x * 256 + threadIdx.x;
    if (idx >= NEDGES) return;
    unsigned int b = (unsigned int)idx / E_;
    unsigned int e = (unsigned int)idx - b * E_;
    int tgt = ei[(size_t)b * 2 * E_ + E_ + e];
    float m = em[(size_t)b * E_ + e];
    if (m != 0.0f)
        atomicAdd(&deg[b * N_ + tgt], 1);
}

// 40 blocks x 256 thr; each block sums 1024 degrees -> bsum[blk]
__global__ __launch_bounds__(256) void scanA_k(
    const int* __restrict__ deg, int* __restrict__ bsum)
{
    __shared__ int wsum[4];
    int t = threadIdx.x;
    int base = blockIdx.x * 1024 + t * 4;
    int s = 0;
    if (base + 3 < NNODES) {
        int4 v = *(const int4*)(deg + base);
        s = v.x + v.y + v.z + v.w;
    } else {
        for (int k = 0; k < 4; ++k) { int i = base + k; if (i < NNODES) s += deg[i]; }
    }
    #pragma unroll
    for (int off = 32; off >= 1; off >>= 1) s += __shfl_xor(s, off, 64);
    int lane = t & 63, wv = t >> 6;
    if (lane == 0) wsum[wv] = s;
    __syncthreads();
    if (t == 0) bsum[blockIdx.x] = wsum[0] + wsum[1] + wsum[2] + wsum[3];
}

// 40 blocks x 256 thr; exclusive scan -> cursor (fill will bump it back to offs+deg)
__global__ __launch_bounds__(256) void scanC_k(
    const int* __restrict__ deg, const int* __restrict__ bsum,
    int* __restrict__ cursor)
{
    __shared__ int wsum[4];
    __shared__ int bb;
    int t = threadIdx.x, blk = blockIdx.x;
    int base = blk * 1024 + t * 4;
    int v0 = 0, v1 = 0, v2 = 0, v3 = 0;
    bool full = (base + 3 < NNODES);
    if (full) {
        int4 q = *(const int4*)(deg + base);
        v0 = q.x; v1 = q.y; v2 = q.z; v3 = q.w;
    } else {
        if (base + 0 < NNODES) v0 = deg[base + 0];
        if (base + 1 < NNODES) v1 = deg[base + 1];
        if (base + 2 < NNODES) v2 = deg[base + 2];
        if (base + 3 < NNODES) v3 = deg[base + 3];
    }
    int ts = v0 + v1 + v2 + v3;
    int lane = t & 63, wv = t >> 6;
    int inc = ts;
    #pragma unroll
    for (int off = 1; off < 64; off <<= 1) {
        int u = __shfl_up(inc, off, 64);
        if (lane >= off) inc += u;
    }
    if (lane == 63) wsum[wv] = inc;
    if (t < 64) {   // wave 0: block base = sum of bsum[0..blk)
        int c = (t < blk) ? bsum[t] : 0;
        #pragma unroll
        for (int off = 32; off >= 1; off >>= 1) c += __shfl_xor(c, off, 64);
        if (t == 0) bb = c;
    }
    __syncthreads();
    int wbase = 0;
    for (int w = 0; w < wv; ++w) wbase += wsum[w];
    int run = bb + wbase + (inc - ts);
    int4 ov;
    ov.x = run;
    ov.y = ov.x + v0;
    ov.z = ov.y + v1;
    ov.w = ov.z + v2;
    if (full) {
        *(int4*)(cursor + base) = ov;
    } else {
        if (base + 0 < NNODES) cursor[base + 0] = ov.x;
        if (base + 1 < NNODES) cursor[base + 1] = ov.y;
        if (base + 2 < NNODES) cursor[base + 2] = ov.z;
        if (base + 3 < NNODES) cursor[base + 3] = ov.w;
    }
}

// entries[slot] = { global_src_row, bitcast(m) }
__global__ __launch_bounds__(256) void fill_k(
    const int* __restrict__ ei, const float* __restrict__ em,
    int* __restrict__ cursor, int2* __restrict__ entries)
{
    int idx = blockIdx.x * 256 + threadIdx.x;
    if (idx >= NEDGES) return;
    unsigned int b = (unsigned int)idx / E_;
    unsigned int e = (unsigned int)idx - b * E_;
    const int* eib = ei + (size_t)b * 2 * E_;
    int src = eib[e];
    int tgt = eib[E_ + e];
    float m = em[(size_t)b * E_ + e];
    if (m != 0.0f) {
        int g = b * N_ + tgt;
        int slot = atomicAdd(&cursor[g], 1);
        entries[slot] = make_int2((int)(b * N_) + src, __float_as_int(m));
    }
}

// ---------- gather: one wave per node, XCD-affinity swizzle ----------
// blockIdx % 8 = batch b  ->  each XCD's x working set is one batch (2.56 MB < 4 MB L2).
__global__ __launch_bounds__(256) void gather_k(
    const float* __restrict__ x, const int* __restrict__ deg,
    const int* __restrict__ cursor, const int2* __restrict__ entries,
    unsigned short* __restrict__ agg)
{
    int wv = threadIdx.x >> 6, lane = threadIdx.x & 63;
    int b = blockIdx.x & 7;
    int i = blockIdx.x >> 3;              // 0..1249
    int g = b * N_ + i * 4 + wv;
    int dg = deg[g];
    int off = cursor[g] - dg;             // cursor ended at offs+deg after fill
    const int2* ep = entries + off;
    float ax0 = 0.f, ay0 = 0.f, ax1 = 0.f, ay1 = 0.f, c0 = 0.f, c1 = 0.f;
    int k = 0;
    for (; k + 1 < dg; k += 2) {
        int2 e0 = ep[k];
        int2 e1 = ep[k + 1];
        float2 v0 = *(const float2*)(x + (size_t)e0.x * D_ + 2 * lane);
        float2 v1 = *(const float2*)(x + (size_t)e1.x * D_ + 2 * lane);
        float m0 = __int_as_float(e0.y), m1 = __int_as_float(e1.y);
        ax0 += v0.x * m0; ay0 += v0.y * m0; c0 += m0;
        ax1 += v1.x * m1; ay1 += v1.y * m1; c1 += m1;
    }
    if (k < dg) {
        int2 e0 = ep[k];
        float2 v0 = *(const float2*)(x + (size_t)e0.x * D_ + 2 * lane);
        float m0 = __int_as_float(e0.y);
        ax0 += v0.x * m0; ay0 += v0.y * m0; c0 += m0;
    }
    float inv = 1.0f / fmaxf(c0 + c1, 1.0f);
    unsigned int pk = (unsigned int)f2bf((ax0 + ax1) * inv)
                    | ((unsigned int)f2bf((ay0 + ay1) * inv) << 16);
    *(unsigned int*)(agg + (size_t)g * D_ + 2 * lane) = pk;
}

// ---------- dual GEMV + ReLU + LayerNorm + mask ----------
// 128 threads (2 waves), 32 nodes/block; phase-2 layout identical to R3 (validated).
__global__ __launch_bounds__(128) void gemv_ln_k(
    const float* __restrict__ x, const unsigned short* __restrict__ agg,
    const float* __restrict__ Wself, const float* __restrict__ bself,
    const float* __restrict__ Wnb, const float* __restrict__ bnb,
    const float* __restrict__ gamma, const float* __restrict__ beta,
    const float* __restrict__ nmask, float* __restrict__ out)
{
    __shared__ float xs[NPB][D_];
    __shared__ float as[NPB][D_];

    int t = threadIdx.x;
    int g0 = blockIdx.x * NPB;

    #pragma unroll 4
    for (int j = 0; j < NPB; ++j) {
        xs[j][t] = x[(size_t)(g0 + j) * D_ + t];
        as[j][t] = bf2f(agg[(size_t)(g0 + j) * D_ + t]);
    }
    __syncthreads();

    int lane = t & 63;
    int wv = t >> 6;
    int grp = wv * 2 + (lane >> 5);
    int c0 = lane & 31;
    int jb = grp * 8;

    float4 bs4 = *(const float4*)(bself + 4 * c0);
    float4 bn4 = *(const float4*)(bnb + 4 * c0);
    float4 accS[8], accN[8];
    #pragma unroll
    for (int jj = 0; jj < 8; ++jj) { accS[jj] = bs4; accN[jj] = bn4; }

    for (int d = 0; d < D_; d += 4) {
        float4 w0 = *(const float4*)(Wself + (size_t)(d + 0) * D_ + 4 * c0);
        float4 w1 = *(const float4*)(Wself + (size_t)(d + 1) * D_ + 4 * c0);
        float4 w2 = *(const float4*)(Wself + (size_t)(d + 2) * D_ + 4 * c0);
        float4 w3 = *(const float4*)(Wself + (size_t)(d + 3) * D_ + 4 * c0);
        float4 u0 = *(const float4*)(Wnb  + (size_t)(d + 0) * D_ + 4 * c0);
        float4 u1 = *(const float4*)(Wnb  + (size_t)(d + 1) * D_ + 4 * c0);
        float4 u2 = *(const float4*)(Wnb  + (size_t)(d + 2) * D_ + 4 * c0);
        float4 u3 = *(const float4*)(Wnb  + (size_t)(d + 3) * D_ + 4 * c0);
        #pragma unroll
        for (int jj = 0; jj < 8; ++jj) {
            float4 xv = *(const float4*)(&xs[jb + jj][d]);
            float4 av = *(const float4*)(&as[jb + jj][d]);
            accS[jj].x += xv.x * w0.x + xv.y * w1.x + xv.z * w2.x + xv.w * w3.x;
            accS[jj].y += xv.x * w0.y + xv.y * w1.y + xv.z * w2.y + xv.w * w3.y;
            accS[jj].z += xv.x * w0.z + xv.y * w1.z + xv.z * w2.z + xv.w * w3.z;
            accS[jj].w += xv.x * w0.w + xv.y * w1.w + xv.z * w2.w + xv.w * w3.w;
            accN[jj].x += av.x * u0.x + av.y * u1.x + av.z * u2.x + av.w * u3.x;
            accN[jj].y += av.x * u0.y + av.y * u1.y + av.z * u2.y + av.w * u3.y;
            accN[jj].z += av.x * u0.z + av.y * u1.z + av.z * u2.z + av.w * u3.z;
            accN[jj].w += av.x * u0.w + av.y * u1.w + av.z * u2.w + av.w * u3.w;
        }
    }

    float4 g4 = *(const float4*)(gamma + 4 * c0);
    float4 b4 = *(const float4*)(beta + 4 * c0);

    #pragma unroll
    for (int jj = 0; jj < 8; ++jj) {
        float4 h;
        h.x = fmaxf(accS[jj].x + accN[jj].x, 0.0f);
        h.y = fmaxf(accS[jj].y + accN[jj].y, 0.0f);
        h.z = fmaxf(accS[jj].z + accN[jj].z, 0.0f);
        h.w = fmaxf(accS[jj].w + accN[jj].w, 0.0f);
        float s = h.x + h.y + h.z + h.w;
        float q = h.x * h.x + h.y * h.y + h.z * h.z + h.w * h.w;
        #pragma unroll
        for (int off = 16; off >= 1; off >>= 1) {
            s += __shfl_xor(s, off, 64);
            q += __shfl_xor(q, off, 64);
        }
        float mu = s * (1.0f / D_);
        float var = q * (1.0f / D_) - mu * mu;
        float rin = rsqrtf(fmaxf(var, 0.0f) + EPS_);
        int g = g0 + jb + jj;
        float mk = nmask[g];
        float4 v;
        v.x = ((h.x - mu) * rin * g4.x + b4.x) * mk;
        v.y = ((h.y - mu) * rin * g4.y + b4.y) * mk;
        v.z = ((h.z - mu) * rin * g4.z + b4.z) * mk;
        v.w = ((h.w - mu) * rin * g4.w + b4.w) * mk;
        *(float4*)(out + (size_t)g * D_ + 4 * c0) = v;
    }
}

extern "C" void kernel_launch(void* const* d_in, const int* in_sizes, int n_in,
                              void* d_out, int out_size, void* d_ws, size_t ws_size,
                              hipStream_t stream)
{
    const float* x     = (const float*)d_in[0];
    const int*   ei    = (const int*)d_in[1];
    const float* nmask = (const float*)d_in[2];
    const float* em    = (const float*)d_in[3];
    const float* Wself = (const float*)d_in[4];
    const float* bself = (const float*)d_in[5];
    const float* Wnb   = (const float*)d_in[6];
    const float* bnb   = (const float*)d_in[7];
    const float* gamma = (const float*)d_in[8];
    const float* beta  = (const float*)d_in[9];
    float* out = (float*)d_out;

    // ws: deg[40000] | cursor[40000] | bsum[64] | entries int2[800000] | agg bf16[40000*128]
    int* deg    = (int*)d_ws;
    int* cursor = deg + NNODES;
    int* bsum   = cursor + NNODES;
    int2* entries = (int2*)(bsum + 64);                        // byte 320256, 8B-aligned
    unsigned short* agg = (unsigned short*)(entries + NEDGES); // byte 6720256, 4B-aligned
    // total ~16.2 MiB

    hipMemsetAsync(deg, 0, NNODES * sizeof(int), stream);

    int blocksE = (NEDGES + 255) / 256;   // 3125
    hist_k<<<blocksE, 256, 0, stream>>>(ei, em, deg);
    scanA_k<<<40, 256, 0, stream>>>(deg, bsum);
    scanC_k<<<40, 256, 0, stream>>>(deg, bsum, cursor);
    fill_k<<<blocksE, 256, 0, stream>>>(ei, em, cursor, entries);
    gather_k<<<1250 * 8, 256, 0, stream>>>(x, deg, cursor, entries, agg);
    gemv_ln_k<<<NNODES / NPB, 128, 0, stream>>>(x, agg, Wself, bself, Wnb, bnb,
                                                gamma, beta, nmask, out);
}

// Round 5
// 239.927 us; speedup vs baseline: 3.6732x; 1.2254x over previous
//
#include <hip/hip_runtime.h>

// GraphSAGE layer: B=8, N=5000, E=100000, D=128. All float tensors f32; edge_index int32.
// Pipeline: memset(deg) -> hist -> scanA/scanC -> fill (CSR) -> gather (bf16 agg)
//           -> packW (Bt[n][k] bf16) -> gemm_ln (MFMA bf16 K=256 + ReLU + LN + mask).
// R4 post-mortem: f32 vector GEMV was 99 us at 26% of vector peak. Fused GEMM via
// [x|agg] @ [Ws;Wn] with mfma_f32_16x16x32_bf16; no LDS, fragments direct from global.

#define B_ 8
#define N_ 5000
#define E_ 100000
#define D_ 128
#define EPS_ 1e-5f
#define NNODES (B_ * N_)  // 40000
#define NEDGES (B_ * E_)  // 800000

typedef __bf16 bf16x8 __attribute__((ext_vector_type(8)));
typedef float  f32x4  __attribute__((ext_vector_type(4)));

static __device__ __forceinline__ unsigned short f2bf(float f) {
    union { float f; unsigned int i; } c; c.f = f;
    unsigned int i = c.i;
    i += 0x7fffu + ((i >> 16) & 1u);
    return (unsigned short)(i >> 16);
}

// ---------- CSR build ----------

__global__ __launch_bounds__(256) void hist_k(
    const int* __restrict__ ei, const float* __restrict__ em,
    int* __restrict__ deg)
{
    int idx = blockIdx.x * 256 + threadIdx.x;
    if (idx >= NEDGES) return;
    unsigned int b = (unsigned int)idx / E_;
    unsigned int e = (unsigned int)idx - b * E_;
    int tgt = ei[(size_t)b * 2 * E_ + E_ + e];
    float m = em[(size_t)b * E_ + e];
    if (m != 0.0f)
        atomicAdd(&deg[b * N_ + tgt], 1);
}

__global__ __launch_bounds__(256) void scanA_k(
    const int* __restrict__ deg, int* __restrict__ bsum)
{
    __shared__ int wsum[4];
    int t = threadIdx.x;
    int base = blockIdx.x * 1024 + t * 4;
    int s = 0;
    if (base + 3 < NNODES) {
        int4 v = *(const int4*)(deg + base);
        s = v.x + v.y + v.z + v.w;
    } else {
        for (int k = 0; k < 4; ++k) { int i = base + k; if (i < NNODES) s += deg[i]; }
    }
    #pragma unroll
    for (int off = 32; off >= 1; off >>= 1) s += __shfl_xor(s, off, 64);
    int lane = t & 63, wv = t >> 6;
    if (lane == 0) wsum[wv] = s;
    __syncthreads();
    if (t == 0) bsum[blockIdx.x] = wsum[0] + wsum[1] + wsum[2] + wsum[3];
}

__global__ __launch_bounds__(256) void scanC_k(
    const int* __restrict__ deg, const int* __restrict__ bsum,
    int* __restrict__ cursor)
{
    __shared__ int wsum[4];
    __shared__ int bb;
    int t = threadIdx.x, blk = blockIdx.x;
    int base = blk * 1024 + t * 4;
    int v0 = 0, v1 = 0, v2 = 0, v3 = 0;
    bool full = (base + 3 < NNODES);
    if (full) {
        int4 q = *(const int4*)(deg + base);
        v0 = q.x; v1 = q.y; v2 = q.z; v3 = q.w;
    } else {
        if (base + 0 < NNODES) v0 = deg[base + 0];
        if (base + 1 < NNODES) v1 = deg[base + 1];
        if (base + 2 < NNODES) v2 = deg[base + 2];
        if (base + 3 < NNODES) v3 = deg[base + 3];
    }
    int ts = v0 + v1 + v2 + v3;
    int lane = t & 63, wv = t >> 6;
    int inc = ts;
    #pragma unroll
    for (int off = 1; off < 64; off <<= 1) {
        int u = __shfl_up(inc, off, 64);
        if (lane >= off) inc += u;
    }
    if (lane == 63) wsum[wv] = inc;
    if (t < 64) {
        int c = (t < blk) ? bsum[t] : 0;
        #pragma unroll
        for (int off = 32; off >= 1; off >>= 1) c += __shfl_xor(c, off, 64);
        if (t == 0) bb = c;
    }
    __syncthreads();
    int wbase = 0;
    for (int w = 0; w < wv; ++w) wbase += wsum[w];
    int run = bb + wbase + (inc - ts);
    int4 ov;
    ov.x = run;
    ov.y = ov.x + v0;
    ov.z = ov.y + v1;
    ov.w = ov.z + v2;
    if (full) {
        *(int4*)(cursor + base) = ov;
    } else {
        if (base + 0 < NNODES) cursor[base + 0] = ov.x;
        if (base + 1 < NNODES) cursor[base + 1] = ov.y;
        if (base + 2 < NNODES) cursor[base + 2] = ov.z;
        if (base + 3 < NNODES) cursor[base + 3] = ov.w;
    }
}

__global__ __launch_bounds__(256) void fill_k(
    const int* __restrict__ ei, const float* __restrict__ em,
    int* __restrict__ cursor, int2* __restrict__ entries)
{
    int idx = blockIdx.x * 256 + threadIdx.x;
    if (idx >= NEDGES) return;
    unsigned int b = (unsigned int)idx / E_;
    unsigned int e = (unsigned int)idx - b * E_;
    const int* eib = ei + (size_t)b * 2 * E_;
    int src = eib[e];
    int tgt = eib[E_ + e];
    float m = em[(size_t)b * E_ + e];
    if (m != 0.0f) {
        int g = b * N_ + tgt;
        int slot = atomicAdd(&cursor[g], 1);
        entries[slot] = make_int2((int)(b * N_) + src, __float_as_int(m));
    }
}

// ---------- gather: one wave per node, XCD-affinity swizzle; bf16 output ----------
__global__ __launch_bounds__(256) void gather_k(
    const float* __restrict__ x, const int* __restrict__ deg,
    const int* __restrict__ cursor, const int2* __restrict__ entries,
    unsigned short* __restrict__ agg)
{
    int wv = threadIdx.x >> 6, lane = threadIdx.x & 63;
    int b = blockIdx.x & 7;
    int i = blockIdx.x >> 3;
    int g = b * N_ + i * 4 + wv;
    int dg = deg[g];
    int off = cursor[g] - dg;
    const int2* ep = entries + off;
    float ax0 = 0.f, ay0 = 0.f, ax1 = 0.f, ay1 = 0.f, c0 = 0.f, c1 = 0.f;
    int k = 0;
    for (; k + 1 < dg; k += 2) {
        int2 e0 = ep[k];
        int2 e1 = ep[k + 1];
        float2 v0 = *(const float2*)(x + (size_t)e0.x * D_ + 2 * lane);
        float2 v1 = *(const float2*)(x + (size_t)e1.x * D_ + 2 * lane);
        float m0 = __int_as_float(e0.y), m1 = __int_as_float(e1.y);
        ax0 += v0.x * m0; ay0 += v0.y * m0; c0 += m0;
        ax1 += v1.x * m1; ay1 += v1.y * m1; c1 += m1;
    }
    if (k < dg) {
        int2 e0 = ep[k];
        float2 v0 = *(const float2*)(x + (size_t)e0.x * D_ + 2 * lane);
        float m0 = __int_as_float(e0.y);
        ax0 += v0.x * m0; ay0 += v0.y * m0; c0 += m0;
    }
    float inv = 1.0f / fmaxf(c0 + c1, 1.0f);
    unsigned int pk = (unsigned int)f2bf((ax0 + ax1) * inv)
                    | ((unsigned int)f2bf((ay0 + ay1) * inv) << 16);
    *(unsigned int*)(agg + (size_t)g * D_ + 2 * lane) = pk;
}

// ---------- weight pack: Bt[n][k] = bf16( k<128 ? Ws[k][n] : Wn[k-128][n] ) ----------
__global__ __launch_bounds__(256) void packW_k(
    const float* __restrict__ Wself, const float* __restrict__ Wnb,
    unsigned short* __restrict__ Bt)
{
    int n = blockIdx.x;        // 0..127
    int k = threadIdx.x;       // 0..255
    float v = (k < 128) ? Wself[(size_t)k * D_ + n] : Wnb[(size_t)(k - 128) * D_ + n];
    Bt[(size_t)n * 256 + k] = f2bf(v);
}

// ---------- MFMA GEMM + ReLU + LayerNorm + mask ----------
// 625 blocks x 256 thr (4 waves). Wave w: rows rw0..rw0+15, cols 0..127 (8 tiles).
// A = [x(f32->bf16) | agg(bf16)], K=256; B = Bt[n][k] bf16.
__global__ __launch_bounds__(256) void gemm_ln_k(
    const float* __restrict__ x, const unsigned short* __restrict__ agg,
    const unsigned short* __restrict__ Bt,
    const float* __restrict__ bself, const float* __restrict__ bnb,
    const float* __restrict__ gamma, const float* __restrict__ beta,
    const float* __restrict__ nmask, float* __restrict__ out)
{
    int lane = threadIdx.x & 63;
    int w = threadIdx.x >> 6;
    int quad = lane >> 4;
    int lcol = lane & 15;
    int rw0 = blockIdx.x * 64 + w * 16;
    int row = rw0 + lcol;                 // A-fragment row (m = lane&15)

    f32x4 acc[8];
    #pragma unroll
    for (int t = 0; t < 8; ++t) acc[t] = (f32x4)0.0f;

    const float* xrow = x + (size_t)row * D_;
    const unsigned short* arow = agg + (size_t)row * D_;

    // K-steps 0..3: A from x (f32 -> bf16 in-register)
    #pragma unroll 2
    for (int kk = 0; kk < 4; ++kk) {
        int kof = kk * 32 + quad * 8;
        float4 xa = *(const float4*)(xrow + kof);
        float4 xb = *(const float4*)(xrow + kof + 4);
        union { unsigned short u[8]; bf16x8 v; } cv;
        cv.u[0] = f2bf(xa.x); cv.u[1] = f2bf(xa.y);
        cv.u[2] = f2bf(xa.z); cv.u[3] = f2bf(xa.w);
        cv.u[4] = f2bf(xb.x); cv.u[5] = f2bf(xb.y);
        cv.u[6] = f2bf(xb.z); cv.u[7] = f2bf(xb.w);
        #pragma unroll
        for (int t = 0; t < 8; ++t) {
            bf16x8 bf = *(const bf16x8*)(Bt + (size_t)(t * 16 + lcol) * 256 + kof);
            acc[t] = __builtin_amdgcn_mfma_f32_16x16x32_bf16(cv.v, bf, acc[t], 0, 0, 0);
        }
    }
    // K-steps 4..7: A from agg (bf16 direct)
    #pragma unroll 2
    for (int kk = 0; kk < 4; ++kk) {
        int kof = kk * 32 + quad * 8;
        bf16x8 af = *(const bf16x8*)(arow + kof);
        #pragma unroll
        for (int t = 0; t < 8; ++t) {
            bf16x8 bf = *(const bf16x8*)(Bt + (size_t)(t * 16 + lcol) * 256 + 128 + kof);
            acc[t] = __builtin_amdgcn_mfma_f32_16x16x32_bf16(af, bf, acc[t], 0, 0, 0);
        }
    }

    // Epilogue: bias + ReLU, row-wise LN (rows live in 16-lane quads), gamma/beta, mask.
    float bsum_[8], gam[8], bet[8];
    #pragma unroll
    for (int t = 0; t < 8; ++t) {
        int col = t * 16 + lcol;
        bsum_[t] = bself[col] + bnb[col];
        gam[t] = gamma[col];
        bet[t] = beta[col];
    }

    float h[8][4];
    float s[4] = {0, 0, 0, 0}, q[4] = {0, 0, 0, 0};
    #pragma unroll
    for (int t = 0; t < 8; ++t) {
        #pragma unroll
        for (int r = 0; r < 4; ++r) {
            float v = fmaxf(acc[t][r] + bsum_[t], 0.0f);
            h[t][r] = v;
            s[r] += v;
            q[r] += v * v;
        }
    }
    #pragma unroll
    for (int r = 0; r < 4; ++r) {
        #pragma unroll
        for (int off = 1; off <= 8; off <<= 1) {
            s[r] += __shfl_xor(s[r], off, 64);
            q[r] += __shfl_xor(q[r], off, 64);
        }
    }
    #pragma unroll
    for (int r = 0; r < 4; ++r) {
        int orow = rw0 + quad * 4 + r;    // C/D layout: row = quad*4 + reg
        float mu = s[r] * (1.0f / D_);
        float var = q[r] * (1.0f / D_) - mu * mu;
        float rin = rsqrtf(fmaxf(var, 0.0f) + EPS_);
        float mk = nmask[orow];
        float* orow_p = out + (size_t)orow * D_;
        #pragma unroll
        for (int t = 0; t < 8; ++t) {
            int col = t * 16 + lcol;
            orow_p[col] = ((h[t][r] - mu) * rin * gam[t] + bet[t]) * mk;
        }
    }
}

extern "C" void kernel_launch(void* const* d_in, const int* in_sizes, int n_in,
                              void* d_out, int out_size, void* d_ws, size_t ws_size,
                              hipStream_t stream)
{
    const float* x     = (const float*)d_in[0];
    const int*   ei    = (const int*)d_in[1];
    const float* nmask = (const float*)d_in[2];
    const float* em    = (const float*)d_in[3];
    const float* Wself = (const float*)d_in[4];
    const float* bself = (const float*)d_in[5];
    const float* Wnb   = (const float*)d_in[6];
    const float* bnb   = (const float*)d_in[7];
    const float* gamma = (const float*)d_in[8];
    const float* beta  = (const float*)d_in[9];
    float* out = (float*)d_out;

    // ws: deg[40000] | cursor[40000] | bsum[64] | entries int2[800000]
    //     | agg bf16[40000*128] | Bt bf16[128*256]   (~17.0 MB total)
    int* deg    = (int*)d_ws;
    int* cursor = deg + NNODES;
    int* bsum   = cursor + NNODES;
    int2* entries = (int2*)(bsum + 64);                         // byte 320256
    unsigned short* agg = (unsigned short*)(entries + NEDGES);  // byte 6720256 (16-al)
    unsigned short* Bt  = agg + (size_t)NNODES * D_;            // byte 16960256 (16-al)

    hipMemsetAsync(deg, 0, NNODES * sizeof(int), stream);

    int blocksE = (NEDGES + 255) / 256;   // 3125
    hist_k<<<blocksE, 256, 0, stream>>>(ei, em, deg);
    scanA_k<<<40, 256, 0, stream>>>(deg, bsum);
    scanC_k<<<40, 256, 0, stream>>>(deg, bsum, cursor);
    fill_k<<<blocksE, 256, 0, stream>>>(ei, em, cursor, entries);
    gather_k<<<1250 * 8, 256, 0, stream>>>(x, deg, cursor, entries, agg);
    packW_k<<<128, 256, 0, stream>>>(Wself, Wnb, Bt);
    gemm_ln_k<<<NNODES / 64, 256, 0, stream>>>(x, agg, Bt, bself, bnb,
                                               gamma, beta, nmask, out);
}

// Round 6
// 225.840 us; speedup vs baseline: 3.9023x; 1.0624x over previous
//
#include <hip/hip_runtime.h>

// GraphSAGE layer: B=8, N=5000, E=100000, D=128. All float tensors f32; edge_index int32.
// Pipeline (6 dispatches): memset(deg) -> prep(hist+packW) -> scan (CSR offsets)
//   -> fill (edge lists) -> gather (4-edge ILP, shfl-broadcast entries, bf16 agg)
//   -> gemm_ln (MFMA bf16 K=256 + ReLU + LN + mask).
// R5 post-mortem: gather latency-bound (VALU 31%, 8.5 TB/s eff L2) -> more ILP;
// launches cut 8->6. gemm/fill/hist kept verbatim (proven, not yet shown hot).

#define B_ 8
#define N_ 5000
#define E_ 100000
#define D_ 128
#define EPS_ 1e-5f
#define NNODES (B_ * N_)  // 40000
#define NEDGES (B_ * E_)  // 800000
#define HIST_BLOCKS (NEDGES / 256)   // 3125 exact

typedef __bf16 bf16x8 __attribute__((ext_vector_type(8)));
typedef float  f32x4  __attribute__((ext_vector_type(4)));

static __device__ __forceinline__ unsigned short f2bf(float f) {
    union { float f; unsigned int i; } c; c.f = f;
    unsigned int i = c.i;
    i += 0x7fffu + ((i >> 16) & 1u);
    return (unsigned short)(i >> 16);
}

// ---------- prep: hist (blocks 0..3124) + weight pack (blocks 3125..3252) ----------
__global__ __launch_bounds__(256) void prep_k(
    const int* __restrict__ ei, const float* __restrict__ em,
    int* __restrict__ deg,
    const float* __restrict__ Wself, const float* __restrict__ Wnb,
    unsigned short* __restrict__ Bt)
{
    if (blockIdx.x < HIST_BLOCKS) {
        int idx = blockIdx.x * 256 + threadIdx.x;
        unsigned int b = (unsigned int)idx / E_;
        unsigned int e = (unsigned int)idx - b * E_;
        int tgt = ei[(size_t)b * 2 * E_ + E_ + e];
        float m = em[(size_t)b * E_ + e];
        if (m != 0.0f)
            atomicAdd(&deg[b * N_ + tgt], 1);
    } else {
        int n = blockIdx.x - HIST_BLOCKS;   // 0..127
        int k = threadIdx.x;                // 0..255
        float v = (k < 128) ? Wself[(size_t)k * D_ + n]
                            : Wnb[(size_t)(k - 128) * D_ + n];
        Bt[(size_t)n * 256 + k] = f2bf(v);
    }
}

// ---------- scan: 40 blocks; each computes its prefix base redundantly, then
// local exclusive scan of its 1024 degrees -> cursor ----------
__global__ __launch_bounds__(256) void scan_k(
    const int* __restrict__ deg, int* __restrict__ cursor)
{
    __shared__ int wsumA[4];
    __shared__ int wsumB[4];
    int t = threadIdx.x, blk = blockIdx.x;
    int lane = t & 63, wv = t >> 6;

    // phase 1: pre = sum(deg[0 .. blk*1024))
    int pre = 0;
    int lim = blk * 1024;
    for (int i = t * 4; i < lim; i += 1024) {
        int4 v = *(const int4*)(deg + i);       // lim multiple of 1024 -> full int4s
        pre += v.x + v.y + v.z + v.w;
    }
    #pragma unroll
    for (int off = 32; off >= 1; off >>= 1) pre += __shfl_xor(pre, off, 64);
    if (lane == 0) wsumA[wv] = pre;
    __syncthreads();
    int bb = wsumA[0] + wsumA[1] + wsumA[2] + wsumA[3];

    // phase 2: local scan of deg[blk*1024 .. blk*1024+1024)
    int base = lim + t * 4;
    int v0 = 0, v1 = 0, v2 = 0, v3 = 0;
    bool full = (base + 3 < NNODES);
    if (full) {
        int4 q = *(const int4*)(deg + base);
        v0 = q.x; v1 = q.y; v2 = q.z; v3 = q.w;
    } else {
        if (base + 0 < NNODES) v0 = deg[base + 0];
        if (base + 1 < NNODES) v1 = deg[base + 1];
        if (base + 2 < NNODES) v2 = deg[base + 2];
        if (base + 3 < NNODES) v3 = deg[base + 3];
    }
    int ts = v0 + v1 + v2 + v3;
    int inc = ts;
    #pragma unroll
    for (int off = 1; off < 64; off <<= 1) {
        int u = __shfl_up(inc, off, 64);
        if (lane >= off) inc += u;
    }
    if (lane == 63) wsumB[wv] = inc;
    __syncthreads();
    int wbase = 0;
    for (int w = 0; w < wv; ++w) wbase += wsumB[w];
    int run = bb + wbase + (inc - ts);
    int4 ov;
    ov.x = run;
    ov.y = ov.x + v0;
    ov.z = ov.y + v1;
    ov.w = ov.z + v2;
    if (full) {
        *(int4*)(cursor + base) = ov;
    } else {
        if (base + 0 < NNODES) cursor[base + 0] = ov.x;
        if (base + 1 < NNODES) cursor[base + 1] = ov.y;
        if (base + 2 < NNODES) cursor[base + 2] = ov.z;
        if (base + 3 < NNODES) cursor[base + 3] = ov.w;
    }
}

// ---------- fill: entries[slot] = { global_src_row, bitcast(m) } ----------
__global__ __launch_bounds__(256) void fill_k(
    const int* __restrict__ ei, const float* __restrict__ em,
    int* __restrict__ cursor, int2* __restrict__ entries)
{
    int idx = blockIdx.x * 256 + threadIdx.x;
    if (idx >= NEDGES) return;
    unsigned int b = (unsigned int)idx / E_;
    unsigned int e = (unsigned int)idx - b * E_;
    const int* eib = ei + (size_t)b * 2 * E_;
    int src = eib[e];
    int tgt = eib[E_ + e];
    float m = em[(size_t)b * E_ + e];
    if (m != 0.0f) {
        int g = b * N_ + tgt;
        int slot = atomicAdd(&cursor[g], 1);
        entries[slot] = make_int2((int)(b * N_) + src, __float_as_int(m));
    }
}

// ---------- gather v3: one wave per node; 4 edges in flight ----------
// Entries prefetched by lanes 0..3 and shfl-broadcast; 32 lanes x float4 per row;
// half = lane>>5 picks which of 2 edges per step; XCD swizzle blockIdx%8 = batch.
__global__ __launch_bounds__(256) void gather_k(
    const float* __restrict__ x, const int* __restrict__ deg,
    const int* __restrict__ cursor, const int2* __restrict__ entries,
    unsigned short* __restrict__ agg)
{
    int wv = threadIdx.x >> 6, lane = threadIdx.x & 63;
    int b = blockIdx.x & 7;
    int i = blockIdx.x >> 3;
    int g = b * N_ + i * 4 + wv;
    int dg = deg[g];
    int off = cursor[g] - dg;              // cursor ended at offs+deg after fill
    const int2* ep = entries + off;

    int half = lane >> 5;                  // 0/1: which edge of the pair
    int c4 = lane & 31;                    // float4 index within the 128-ch row

    float4 acc = make_float4(0.f, 0.f, 0.f, 0.f);
    float cnt = 0.f;

    int2 ee = (lane < 4 && lane < dg) ? ep[lane] : make_int2(0, 0);
    int k = 0;
    for (; k + 4 <= dg; k += 4) {
        int2 een = (lane < 4 && k + 4 + lane < dg) ? ep[k + 4 + lane]
                                                   : make_int2(0, 0);
        int   s0 = __shfl(ee.x, half, 64);
        float m0 = __int_as_float(__shfl(ee.y, half, 64));
        int   s1 = __shfl(ee.x, 2 + half, 64);
        float m1 = __int_as_float(__shfl(ee.y, 2 + half, 64));
        float4 v0 = *(const float4*)(x + (size_t)s0 * D_ + 4 * c4);
        float4 v1 = *(const float4*)(x + (size_t)s1 * D_ + 4 * c4);
        acc.x += v0.x * m0 + v1.x * m1;
        acc.y += v0.y * m0 + v1.y * m1;
        acc.z += v0.z * m0 + v1.z * m1;
        acc.w += v0.w * m0 + v1.w * m1;
        cnt += m0 + m1;
        ee = een;
    }
    int rem = dg - k;                      // 0..3
    if (rem > 0) {
        int   s0 = __shfl(ee.x, half, 64);
        float m0 = __int_as_float(__shfl(ee.y, half, 64));
        int   s1 = __shfl(ee.x, 2 + half, 64);
        float m1 = __int_as_float(__shfl(ee.y, 2 + half, 64));
        if (half < rem) {
            float4 v0 = *(const float4*)(x + (size_t)s0 * D_ + 4 * c4);
            acc.x += v0.x * m0; acc.y += v0.y * m0;
            acc.z += v0.z * m0; acc.w += v0.w * m0;
            cnt += m0;
        }
        if (2 + half < rem) {
            float4 v1 = *(const float4*)(x + (size_t)s1 * D_ + 4 * c4);
            acc.x += v1.x * m1; acc.y += v1.y * m1;
            acc.z += v1.z * m1; acc.w += v1.w * m1;
            cnt += m1;
        }
    }

    // combine the two half-wave partials
    acc.x += __shfl_xor(acc.x, 32, 64);
    acc.y += __shfl_xor(acc.y, 32, 64);
    acc.z += __shfl_xor(acc.z, 32, 64);
    acc.w += __shfl_xor(acc.w, 32, 64);
    cnt   += __shfl_xor(cnt, 32, 64);

    if (lane < 32) {
        float inv = 1.0f / fmaxf(cnt, 1.0f);
        uint2 pk;
        pk.x = (unsigned int)f2bf(acc.x * inv) | ((unsigned int)f2bf(acc.y * inv) << 16);
        pk.y = (unsigned int)f2bf(acc.z * inv) | ((unsigned int)f2bf(acc.w * inv) << 16);
        *(uint2*)(agg + (size_t)g * D_ + 4 * c4) = pk;
    }
}

// ---------- MFMA GEMM + ReLU + LayerNorm + mask (R5-proven) ----------
__global__ __launch_bounds__(256) void gemm_ln_k(
    const float* __restrict__ x, const unsigned short* __restrict__ agg,
    const unsigned short* __restrict__ Bt,
    const float* __restrict__ bself, const float* __restrict__ bnb,
    const float* __restrict__ gamma, const float* __restrict__ beta,
    const float* __restrict__ nmask, float* __restrict__ out)
{
    int lane = threadIdx.x & 63;
    int w = threadIdx.x >> 6;
    int quad = lane >> 4;
    int lcol = lane & 15;
    int rw0 = blockIdx.x * 64 + w * 16;
    int row = rw0 + lcol;

    f32x4 acc[8];
    #pragma unroll
    for (int t = 0; t < 8; ++t) acc[t] = (f32x4)0.0f;

    const float* xrow = x + (size_t)row * D_;
    const unsigned short* arow = agg + (size_t)row * D_;

    #pragma unroll 2
    for (int kk = 0; kk < 4; ++kk) {
        int kof = kk * 32 + quad * 8;
        float4 xa = *(const float4*)(xrow + kof);
        float4 xb = *(const float4*)(xrow + kof + 4);
        union { unsigned short u[8]; bf16x8 v; } cv;
        cv.u[0] = f2bf(xa.x); cv.u[1] = f2bf(xa.y);
        cv.u[2] = f2bf(xa.z); cv.u[3] = f2bf(xa.w);
        cv.u[4] = f2bf(xb.x); cv.u[5] = f2bf(xb.y);
        cv.u[6] = f2bf(xb.z); cv.u[7] = f2bf(xb.w);
        #pragma unroll
        for (int t = 0; t < 8; ++t) {
            bf16x8 bf = *(const bf16x8*)(Bt + (size_t)(t * 16 + lcol) * 256 + kof);
            acc[t] = __builtin_amdgcn_mfma_f32_16x16x32_bf16(cv.v, bf, acc[t], 0, 0, 0);
        }
    }
    #pragma unroll 2
    for (int kk = 0; kk < 4; ++kk) {
        int kof = kk * 32 + quad * 8;
        bf16x8 af = *(const bf16x8*)(arow + kof);
        #pragma unroll
        for (int t = 0; t < 8; ++t) {
            bf16x8 bf = *(const bf16x8*)(Bt + (size_t)(t * 16 + lcol) * 256 + 128 + kof);
            acc[t] = __builtin_amdgcn_mfma_f32_16x16x32_bf16(af, bf, acc[t], 0, 0, 0);
        }
    }

    float bsum_[8], gam[8], bet[8];
    #pragma unroll
    for (int t = 0; t < 8; ++t) {
        int col = t * 16 + lcol;
        bsum_[t] = bself[col] + bnb[col];
        gam[t] = gamma[col];
        bet[t] = beta[col];
    }

    float h[8][4];
    float s[4] = {0, 0, 0, 0}, q[4] = {0, 0, 0, 0};
    #pragma unroll
    for (int t = 0; t < 8; ++t) {
        #pragma unroll
        for (int r = 0; r < 4; ++r) {
            float v = fmaxf(acc[t][r] + bsum_[t], 0.0f);
            h[t][r] = v;
            s[r] += v;
            q[r] += v * v;
        }
    }
    #pragma unroll
    for (int r = 0; r < 4; ++r) {
        #pragma unroll
        for (int off = 1; off <= 8; off <<= 1) {
            s[r] += __shfl_xor(s[r], off, 64);
            q[r] += __shfl_xor(q[r], off, 64);
        }
    }
    #pragma unroll
    for (int r = 0; r < 4; ++r) {
        int orow = rw0 + quad * 4 + r;
        float mu = s[r] * (1.0f / D_);
        float var = q[r] * (1.0f / D_) - mu * mu;
        float rin = rsqrtf(fmaxf(var, 0.0f) + EPS_);
        float mk = nmask[orow];
        float* orow_p = out + (size_t)orow * D_;
        #pragma unroll
        for (int t = 0; t < 8; ++t) {
            int col = t * 16 + lcol;
            orow_p[col] = ((h[t][r] - mu) * rin * gam[t] + bet[t]) * mk;
        }
    }
}

extern "C" void kernel_launch(void* const* d_in, const int* in_sizes, int n_in,
                              void* d_out, int out_size, void* d_ws, size_t ws_size,
                              hipStream_t stream)
{
    const float* x     = (const float*)d_in[0];
    const int*   ei    = (const int*)d_in[1];
    const float* nmask = (const float*)d_in[2];
    const float* em    = (const float*)d_in[3];
    const float* Wself = (const float*)d_in[4];
    const float* bself = (const float*)d_in[5];
    const float* Wnb   = (const float*)d_in[6];
    const float* bnb   = (const float*)d_in[7];
    const float* gamma = (const float*)d_in[8];
    const float* beta  = (const float*)d_in[9];
    float* out = (float*)d_out;

    // ws: deg[40000] | cursor[40000] | entries int2[800000]
    //     | agg bf16[40000*128] | Bt bf16[128*256]   (~17.0 MB, proven size)
    int* deg    = (int*)d_ws;
    int* cursor = deg + NNODES;
    int2* entries = (int2*)(cursor + NNODES);                   // byte 320000, 8-al
    unsigned short* agg = (unsigned short*)(entries + NEDGES);  // byte 6720000, 16-al
    unsigned short* Bt  = agg + (size_t)NNODES * D_;            // byte 16960000, 16-al

    hipMemsetAsync(deg, 0, NNODES * sizeof(int), stream);

    prep_k<<<HIST_BLOCKS + 128, 256, 0, stream>>>(ei, em, deg, Wself, Wnb, Bt);
    scan_k<<<40, 256, 0, stream>>>(deg, cursor);
    fill_k<<<HIST_BLOCKS, 256, 0, stream>>>(ei, em, cursor, entries);
    gather_k<<<1250 * 8, 256, 0, stream>>>(x, deg, cursor, entries, agg);
    gemm_ln_k<<<NNODES / 64, 256, 0, stream>>>(x, agg, Bt, bself, bnb,
                                               gamma, beta, nmask, out);
}